// Round 11
// baseline (278.576 us; speedup 1.0000x reference)
//
#include <hip/hip_runtime.h>
#include <math.h>

#define B_ 8
#define L_ 336
#define H_ 192
#define C_ 321
#define K_ 16
#define S_ 8
#define H2_ 97
#define OUT_ 3201
#define SEQLEN_ 528
#define BC_ (B_ * C_)
#define JD_ 136
#define MIXJ_ 291
#define NP_ 208
#define MROWS_ 43656
#define KF_ 160
#define MPADF_ 2576
#define NPADF_ 3264
#define KMX_ 608
#define NMX_ 208
#define KIR_ 224
#define NIR_ 192

typedef float v2f __attribute__((ext_vector_type(2)));
typedef float v4f __attribute__((ext_vector_type(4)));
typedef __attribute__((ext_vector_type(8))) short bf16x8;
typedef __attribute__((ext_vector_type(4))) float f32x4;

#define TWO_PI_F 6.283185307179586f

// ws layout (float units) — no overlays, ~88 MB total (ws is 256 MB)
static constexpr size_t OFF_SEQ  = 0;
static constexpr size_t OFF_MU   = OFF_SEQ + (size_t)BC_ * SEQLEN_;
static constexpr size_t OFF_STD  = OFF_MU + BC_;
static constexpr size_t OFF_BPHI = (OFF_STD + BC_ + 3) & ~(size_t)3;
static constexpr size_t OFF_BPLO = OFF_BPHI + (size_t)NP_ * 192 / 2;
static constexpr size_t OFF_UHI  = OFF_BPLO + (size_t)NP_ * 192 / 2;
static constexpr size_t OFF_ULO  = OFF_UHI + (size_t)MPADF_ * KF_ / 2;
static constexpr size_t OFF_W2HI = OFF_ULO + (size_t)MPADF_ * KF_ / 2;
static constexpr size_t OFF_W2LO = OFF_W2HI + (size_t)NPADF_ * KF_ / 2;
static constexpr size_t OFF_MWHI = OFF_W2LO + (size_t)NPADF_ * KF_ / 2;
static constexpr size_t OFF_MWLO = OFF_MWHI + (size_t)NMX_ * KMX_ / 2;
static constexpr size_t OFF_THI  = OFF_MWLO + (size_t)NMX_ * KMX_ / 2;
static constexpr size_t OFF_TLO  = OFF_THI + (size_t)NIR_ * KIR_ / 2;
static constexpr size_t OFF_F    = OFF_TLO + (size_t)NIR_ * KIR_ / 2;
static constexpr size_t OFF_FILT = OFF_F + (size_t)MROWS_ * NP_;
static constexpr size_t OFF_MXHI = OFF_FILT + (size_t)BC_ * OUT_;
static constexpr size_t OFF_MXLO = OFF_MXHI + (size_t)MPADF_ * KMX_ / 2;
static constexpr size_t OFF_ZHI  = OFF_MXLO + (size_t)MPADF_ * KMX_ / 2;
static constexpr size_t OFF_ZLO  = OFF_ZHI + (size_t)MPADF_ * KIR_ / 2;

__device__ inline void split_bf16(float v, unsigned short& hh, unsigned short& ll) {
  unsigned u = __float_as_uint(v);
  unsigned hb = (u + 0x7FFFu + ((u >> 16) & 1u)) & 0xFFFF0000u;
  float fh = __uint_as_float(hb);
  float fl = v - fh;
  unsigned u2 = __float_as_uint(fl);
  unsigned lb = (u2 + 0x7FFFu + ((u2 >> 16) & 1u)) >> 16;
  hh = (unsigned short)(hb >> 16);
  ll = (unsigned short)lb;
}

// ---------------------------------------------------------------------------
// kPre: stats + cls softmax + corr_feat + U planes + normalized seq transpose.
// Block = (b, 64-c tile), 256 thr.
// ---------------------------------------------------------------------------
__launch_bounds__(256)
__global__ void kPre(const float* __restrict__ x, const float* __restrict__ y_hat,
                     const float* __restrict__ cls_w, const float* __restrict__ cls_bias,
                     const float* __restrict__ basic_state, const float* __restrict__ r,
                     const float* __restrict__ temperature,
                     float* __restrict__ mu, float* __restrict__ stdv,
                     unsigned short* __restrict__ uhi, unsigned short* __restrict__ ulo,
                     float* __restrict__ seq) {
  __shared__ float part[4][10][64];
  __shared__ float sp[64][S_];
  __shared__ float scf[64][K_];
  __shared__ float smu[64], sis[64];
  __shared__ float tile[64][33];

  int b = blockIdx.x;
  int cb = blockIdx.y * 64;
  int lane = threadIdx.x & 63;
  int wv = threadIdx.x >> 6;
  int c = cb + lane;
  bool cok = c < C_;

  float sum = 0.f, sumsq = 0.f, a[S_];
#pragma unroll
  for (int s = 0; s < S_; s++) a[s] = 0.f;
  if (cok) {
    for (int l = wv * 84; l < wv * 84 + 84; l++) {
      float v = x[((size_t)b * L_ + l) * C_ + c];
      sum += v;
      sumsq = fmaf(v, v, sumsq);
#pragma unroll
      for (int s = 0; s < S_; s++) a[s] = fmaf(v, cls_w[s * L_ + l], a[s]);
    }
  }
  part[wv][0][lane] = sum;
  part[wv][1][lane] = sumsq;
#pragma unroll
  for (int s = 0; s < S_; s++) part[wv][2 + s][lane] = a[s];
  __syncthreads();

  if (threadIdx.x < 64 && cok) {
    float s0 = 0.f, s1 = 0.f, ac[S_];
#pragma unroll
    for (int s = 0; s < S_; s++) ac[s] = 0.f;
#pragma unroll
    for (int w = 0; w < 4; w++) {
      s0 += part[w][0][lane];
      s1 += part[w][1][lane];
#pragma unroll
      for (int s = 0; s < S_; s++) ac[s] += part[w][2 + s][lane];
    }
    float m = s0 * (1.f / L_);
    float var = fmaxf(s1 * (1.f / L_) - m * m, 0.f);
    float sd = sqrtf(var + 1e-8f);
    int bc = b * C_ + c;
    mu[bc] = m;
    stdv[bc] = sd;
    smu[lane] = m;
    sis[lane] = 1.f / sd;

    float lg[S_], mx = -1e30f;
#pragma unroll
    for (int s = 0; s < S_; s++) {
      lg[s] = ac[s] + cls_bias[s] + basic_state[c * S_ + s];
      mx = fmaxf(mx, lg[s]);
    }
    float den = 0.f;
#pragma unroll
    for (int s = 0; s < S_; s++) { float e = expf(lg[s] - mx); lg[s] = e; den += e; }
    float iden = 1.f / den;
#pragma unroll
    for (int s = 0; s < S_; s++) sp[lane][s] = lg[s] * iden;

    float it = 1.f / temperature[0];
    float aa[K_], am = it;
#pragma unroll
    for (int k = 0; k < K_; k++) {
      aa[k] = fabsf(r[(size_t)bc * K_ + k]) * it;
      am = fmaxf(am, aa[k]);
    }
    float den2 = expf(it - am);
#pragma unroll
    for (int k = 0; k < K_; k++) { float e = expf(aa[k] - am); aa[k] = e; den2 += e; }
    float iden2 = 1.f / den2;
#pragma unroll
    for (int k = 0; k < K_; k++) scf[lane][k] = aa[k] * iden2;
  }
  __syncthreads();

  // U planes: bf16 hi/lo, K padded to KF_
  for (int idx = threadIdx.x; idx < 64 * KF_; idx += 256) {
    int ci = idx / KF_;
    int j = idx - ci * KF_;
    if (cb + ci < C_) {
      float v = 0.f;
      if (j < JD_) {
        int s = j / 17;
        int t = j - s * 17;
        v = sp[ci][s];
        if (t < K_) v *= scf[ci][t];
      }
      unsigned short hh, ll;
      split_bf16(v, hh, ll);
      size_t rowi = (size_t)(b * C_ + cb + ci) * KF_ + j;
      uhi[rowi] = hh;
      ulo[rowi] = ll;
    }
  }

  // normalized seq transpose, 32-t chunks
  for (int t0 = 0; t0 < SEQLEN_; t0 += 32) {
    int nmax = (SEQLEN_ - t0 < 32) ? (SEQLEN_ - t0) : 32;
    for (int tt = wv; tt < nmax; tt += 4) {
      int t = t0 + tt;
      float v = 0.f;
      if (cok) {
        v = (t < L_) ? x[((size_t)b * L_ + t) * C_ + c]
                     : y_hat[((size_t)b * H_ + (t - L_)) * C_ + c];
        v = (v - smu[lane]) * sis[lane];
      }
      tile[lane][tt] = v;
    }
    __syncthreads();
    int tpos = threadIdx.x & 31;
    if (tpos < nmax) {
      for (int ci = (int)(threadIdx.x >> 5); ci < 64; ci += 8) {
        if (cb + ci < C_)
          seq[((size_t)b * C_ + cb + ci) * SEQLEN_ + t0 + tpos] = tile[ci][tpos];
      }
    }
    __syncthreads();
  }
}

// ---------------------------------------------------------------------------
// kPackAll: all 4 constant-matrix packs in one launch.
// ---------------------------------------------------------------------------
__global__ void kPackAll(const float* __restrict__ mh_w, const float* __restrict__ mh_b,
                         const float* __restrict__ mwr, const float* __restrict__ mwi,
                         const float* __restrict__ mbr, const float* __restrict__ mbi,
                         unsigned short* __restrict__ bhi, unsigned short* __restrict__ blo,
                         unsigned short* __restrict__ w2hi, unsigned short* __restrict__ w2lo,
                         unsigned short* __restrict__ mwhi, unsigned short* __restrict__ mwlo,
                         unsigned short* __restrict__ thi, unsigned short* __restrict__ tlo) {
  const int T1 = NP_ * 192;
  const int T2 = T1 + NPADF_ * KF_;
  const int T3 = T2 + NMX_ * KMX_;
  const int T4 = T3 + NIR_ * KIR_;
  int i = blockIdx.x * 256 + threadIdx.x;
  if (i >= T4) return;
  float v = 0.f;
  unsigned short* dhi;
  unsigned short* dlo;
  int didx;
  if (i < T1) {
    int n = i / 192, h = i - n * 192;
    if (n < H2_) {
      int ph = (n * h) % 192;
      v = cosf((TWO_PI_F / 192.f) * (float)ph);
    } else if (n >= 104 && n < 104 + H2_) {
      int ph = ((n - 104) * h) % 192;
      v = -sinf((TWO_PI_F / 192.f) * (float)ph);
    }
    dhi = bhi; dlo = blo; didx = i;
  } else if (i < T2) {
    int idx = i - T1;
    int n = idx / KF_, k = idx - n * KF_;
    if (n < OUT_ && k < JD_) {
      int s = k / 17, t = k - s * 17;
      v = (t < K_) ? mh_w[(size_t)s * (K_ * OUT_) + (size_t)t * OUT_ + n]
                   : mh_b[(size_t)s * OUT_ + n];
    }
    dhi = w2hi; dlo = w2lo; didx = idx;
  } else if (i < T3) {
    int idx = i - T2;
    int n = idx / KMX_, k = idx - n * KMX_;
    if (n < H2_) {
      int g = n;
      if (k < MIXJ_) v = mwr[(size_t)g * MIXJ_ + k];
      else if (k < 2 * MIXJ_) v = -mwi[(size_t)g * MIXJ_ + (k - MIXJ_)];
      else if (k == 2 * MIXJ_) v = mbr[g];
    } else if (n >= 104 && n < 104 + H2_) {
      int g = n - 104;
      if (k < MIXJ_) v = mwi[(size_t)g * MIXJ_ + k];
      else if (k < 2 * MIXJ_) v = mwr[(size_t)g * MIXJ_ + (k - MIXJ_)];
      else if (k == 2 * MIXJ_) v = mbi[g];
    }
    dhi = mwhi; dlo = mwlo; didx = idx;
  } else {
    int idx = i - T3;
    int h = idx / KIR_, k = idx - h * KIR_;
    if (k < H2_) {
      int f = k;
      float w = (f == 0 || f == 96) ? (1.f / 192.f) : (2.f / 192.f);
      int ph = (f * h) % 192;
      v = w * cosf((TWO_PI_F / 192.f) * (float)ph);
    } else if (k >= 104 && k < 104 + H2_) {
      int f = k - 104;
      if (f != 0 && f != 96) {
        int ph = (f * h) % 192;
        v = -(2.f / 192.f) * sinf((TWO_PI_F / 192.f) * (float)ph);
      }
    }
    dhi = thi; dlo = tlo; didx = idx;
  }
  unsigned short hh, ll;
  split_bf16(v, hh, ll);
  dhi[didx] = hh;
  dlo[didx] = ll;
}

// ---------------------------------------------------------------------------
// kGatherDFT: fused leader-gather + DFT GEMM.  Block = 4 bc (68 rows, pad 80),
// 5 waves (320 thr).  A gathered into LDS bf16 planes [80][200]; B staged in
// LDS (3 K-parts of 52 KB).  Eliminates the rows planes (67 MB traffic).
// ---------------------------------------------------------------------------
__launch_bounds__(320)
__global__ void kGatherDFT(const float* __restrict__ seq, const int* __restrict__ lead,
                           const int* __restrict__ shiftv, const float* __restrict__ r,
                           const unsigned short* __restrict__ bhi,
                           const unsigned short* __restrict__ blo,
                           float* __restrict__ F) {
  __shared__ __align__(16) unsigned short Ah[80 * 200];
  __shared__ __align__(16) unsigned short Al[80 * 200];
  __shared__ __align__(16) unsigned short Bs[52 * 512];
  __shared__ int soff[68];
  __shared__ float ssgn[68];

  int tid = threadIdx.x;
  int wv = tid >> 6;        // 0..4
  int lane = tid & 63;
  int bc0 = blockIdx.x * 4;

  if (tid < 68) {
    int lr = tid;
    int bcl = lr / 17;
    int k = lr - bcl * 17;
    int bc = bc0 + bcl;
    int b = bc / C_;
    int off;
    float sg;
    if (k < K_) {
      int ld = lead[(size_t)bc * K_ + k];
      int sh = shiftv[(size_t)bc * K_ + k];
      float rv = r[(size_t)bc * K_ + k];
      sg = (rv > 0.f) ? 1.f : ((rv < 0.f) ? -1.f : 0.f);
      off = (b * C_ + ld) * SEQLEN_ + (L_ - sh);
    } else {
      sg = 1.f;
      off = bc * SEQLEN_ + L_;
    }
    soff[lr] = off;
    ssgn[lr] = sg;
  }
  __syncthreads();

  for (int idx = tid; idx < 68 * 192; idx += 320) {
    int lr = idx / 192;
    int h = idx - lr * 192;
    float v = seq[soff[lr] + h] * ssgn[lr];
    unsigned short hh, ll;
    split_bf16(v, hh, ll);
    Ah[lr * 200 + h] = hh;
    Al[lr * 200 + h] = ll;
  }
  for (int i = 68 * 200 + tid; i < 80 * 200; i += 320) { Ah[i] = 0; Al[i] = 0; }

  int row = lane & 15;
  int kg = lane >> 4;
  f32x4 acc[13];
#pragma unroll
  for (int nt = 0; nt < 13; nt++) acc[nt] = (f32x4){0.f, 0.f, 0.f, 0.f};

  const unsigned short* Abh = Ah + (wv * 16 + row) * 200 + kg * 8;
  const unsigned short* Abl = Al + (wv * 16 + row) * 200 + kg * 8;

#pragma unroll 1
  for (int part = 0; part < 3; part++) {
    __syncthreads();
    for (int s = wv; s < 52; s += 5) {
      int plane = s & 1;
      int ntks = s >> 1;
      int nt = ntks >> 1;
      int ks2 = ntks & 1;
      const unsigned short* src = (plane ? blo : bhi)
          + (size_t)(nt * 16 + row) * 192 + part * 64 + ks2 * 32 + kg * 8;
      *(bf16x8*)(Bs + s * 512 + lane * 8) = *(const bf16x8*)src;
    }
    __syncthreads();
#pragma unroll
    for (int ks2 = 0; ks2 < 2; ks2++) {
      int ksg = part * 2 + ks2;
      bf16x8 ah = *(const bf16x8*)(Abh + ksg * 32);
      bf16x8 al = *(const bf16x8*)(Abl + ksg * 32);
#pragma unroll
      for (int nt = 0; nt < 13; nt++) {
        bf16x8 bh = *(const bf16x8*)(Bs + ((nt * 2 + ks2) * 2 + 0) * 512 + lane * 8);
        bf16x8 bl = *(const bf16x8*)(Bs + ((nt * 2 + ks2) * 2 + 1) * 512 + lane * 8);
        acc[nt] = __builtin_amdgcn_mfma_f32_16x16x32_bf16(ah, bh, acc[nt], 0, 0, 0);
        acc[nt] = __builtin_amdgcn_mfma_f32_16x16x32_bf16(ah, bl, acc[nt], 0, 0, 0);
        acc[nt] = __builtin_amdgcn_mfma_f32_16x16x32_bf16(al, bh, acc[nt], 0, 0, 0);
      }
    }
  }

  int ml0 = wv * 16 + kg * 4;
#pragma unroll
  for (int nt = 0; nt < 13; nt++) {
#pragma unroll
    for (int rr = 0; rr < 4; rr++) {
      int ml = ml0 + rr;
      if (ml < 68)
        F[((size_t)bc0 * 17 + ml) * NP_ + nt * 16 + row] = acc[nt][rr];
    }
  }
}

// ---------------------------------------------------------------------------
// kFiltMM: filt GEMM, W2 tile staged in LDS (40 KB).  (unchanged, validated)
// ---------------------------------------------------------------------------
__launch_bounds__(256)
__global__ void kFiltMM(const unsigned short* __restrict__ uhi,
                        const unsigned short* __restrict__ ulo,
                        const unsigned short* __restrict__ w2hi,
                        const unsigned short* __restrict__ w2lo,
                        float* __restrict__ filt) {
  __shared__ __align__(16) unsigned short Ws[40 * 512];
  int tid = threadIdx.x;
  int wv = tid >> 6;
  int lane = tid & 63;
  int m0 = (blockIdx.y * 4 + wv) * 16;
  int n0 = blockIdx.x * 64;
  int col = lane & 15;
  int kg = lane >> 4;

  for (int s = wv; s < 40; s += 4) {
    int plane = s & 1;
    int ntk = s >> 1;
    int nt = ntk / 5;
    int ksi = ntk - nt * 5;
    const unsigned short* src = (plane ? w2lo : w2hi)
        + (size_t)(n0 + nt * 16 + col) * KF_ + ksi * 32 + kg * 8;
    *(bf16x8*)(Ws + s * 512 + lane * 8) = *(const bf16x8*)src;
  }
  __syncthreads();

  f32x4 acc[4];
#pragma unroll
  for (int nt = 0; nt < 4; nt++) acc[nt] = (f32x4){0.f, 0.f, 0.f, 0.f};

  int mrow = (m0 + col < MPADF_) ? (m0 + col) : (MPADF_ - 1);
  const unsigned short* Ahp = uhi + (size_t)mrow * KF_ + kg * 8;
  const unsigned short* Alp = ulo + (size_t)mrow * KF_ + kg * 8;

#pragma unroll
  for (int ks = 0; ks < 5; ks++) {
    bf16x8 ah = *(const bf16x8*)(Ahp + ks * 32);
    bf16x8 al = *(const bf16x8*)(Alp + ks * 32);
#pragma unroll
    for (int nt = 0; nt < 4; nt++) {
      bf16x8 bh = *(const bf16x8*)(Ws + ((nt * 5 + ks) * 2 + 0) * 512 + lane * 8);
      bf16x8 bl = *(const bf16x8*)(Ws + ((nt * 5 + ks) * 2 + 1) * 512 + lane * 8);
      acc[nt] = __builtin_amdgcn_mfma_f32_16x16x32_bf16(ah, bh, acc[nt], 0, 0, 0);
      acc[nt] = __builtin_amdgcn_mfma_f32_16x16x32_bf16(ah, bl, acc[nt], 0, 0, 0);
      acc[nt] = __builtin_amdgcn_mfma_f32_16x16x32_bf16(al, bh, acc[nt], 0, 0, 0);
    }
  }

  int crow0 = m0 + kg * 4;
#pragma unroll
  for (int nt = 0; nt < 4; nt++) {
    int o = n0 + nt * 16 + col;
    if (o < OUT_) {
#pragma unroll
      for (int rr = 0; rr < 4; rr++) {
        int m = crow0 + rr;
        if (m < BC_) filt[(size_t)m * OUT_ + o] = acc[nt][rr];
      }
    }
  }
}

// ---------------------------------------------------------------------------
// kCombine: per bc (128 thr): filt combine -> mix_in bf16 planes. (unchanged)
// ---------------------------------------------------------------------------
__launch_bounds__(128)
__global__ void kCombine(const float* __restrict__ F, const float* __restrict__ filt,
                         unsigned short* __restrict__ mxhi, unsigned short* __restrict__ mxlo) {
  int bc = blockIdx.x;
  int ff = threadIdx.x;
  size_t mrowK = (size_t)bc * KMX_;

  if (ff < H2_) {
    float Fre[17], Fim[17];
#pragma unroll
    for (int k = 0; k < 17; k++) {
      size_t mr = (size_t)(bc * 17 + k) * NP_;
      Fre[k] = F[mr + ff];
      Fim[k] = F[mr + 104 + ff];
    }
    const float* fb = filt + (size_t)bc * OUT_;
    float yfR = Fre[16], yfI = Fim[16];
    float S1r = 0.f, S1i = 0.f, S2r = 0.f, S2i = 0.f, sg2 = 0.f;
#pragma unroll
    for (int k = 0; k < K_; k++) {
      float g1 = fb[k * H2_ + ff];
      float g2 = fb[(K_ + k) * H2_ + ff];
      float g12 = g1 * g2;
      S1r = fmaf(Fre[k], g1, S1r);
      S1i = fmaf(Fim[k], g1, S1i);
      S2r = fmaf(Fre[k], g12, S2r);
      S2i = fmaf(Fim[k], g12, S2i);
      sg2 += g2;
    }
    S2r = fmaf(-yfR, sg2, S2r);
    S2i = fmaf(-yfI, sg2, S2i);
    float g3 = fb[32 * H2_ + ff];
    float vals[6] = {S1r, S2r, yfR * g3, S1i, S2i, yfI * g3};
#pragma unroll
    for (int q = 0; q < 6; q++) {
      unsigned short hh, ll;
      split_bf16(vals[q], hh, ll);
      mxhi[mrowK + q * H2_ + ff] = hh;
      mxlo[mrowK + q * H2_ + ff] = ll;
    }
  } else if (ff == H2_) {
    mxhi[mrowK + 2 * MIXJ_] = 0x3F80;  // bf16(1.0) bias
    mxlo[mrowK + 2 * MIXJ_] = 0;
  } else if (ff >= 98 && ff < 98 + (KMX_ - 583)) {
    int k = 583 + (ff - 98);
    mxhi[mrowK + k] = 0;
    mxlo[mrowK + k] = 0;
  }
}

// ---------------------------------------------------------------------------
// kMixMM: z GEMM (unchanged, validated).
// ---------------------------------------------------------------------------
__launch_bounds__(256)
__global__ void kMixMM(const unsigned short* __restrict__ mxhi,
                       const unsigned short* __restrict__ mxlo,
                       const unsigned short* __restrict__ mwhi,
                       const unsigned short* __restrict__ mwlo,
                       unsigned short* __restrict__ zhi, unsigned short* __restrict__ zlo) {
  __shared__ __align__(16) unsigned short Bs[38 * 512];
  int tid = threadIdx.x;
  int wv = tid >> 6;
  int lane = tid & 63;
  int nt = blockIdx.x;
  int m0 = (blockIdx.y * 4 + wv) * 16;
  int row = lane & 15;
  int kg = lane >> 4;

  for (int s = wv; s < 38; s += 4) {
    int plane = s & 1;
    int ks = s >> 1;
    const unsigned short* src = (plane ? mwlo : mwhi)
        + (size_t)(nt * 16 + row) * KMX_ + ks * 32 + kg * 8;
    *(bf16x8*)(Bs + s * 512 + lane * 8) = *(const bf16x8*)src;
  }
  __syncthreads();

  if (m0 >= MPADF_) return;

  f32x4 acc = (f32x4){0.f, 0.f, 0.f, 0.f};
  const unsigned short* Ahp = mxhi + (size_t)(m0 + row) * KMX_ + kg * 8;
  const unsigned short* Alp = mxlo + (size_t)(m0 + row) * KMX_ + kg * 8;

#pragma unroll
  for (int ks = 0; ks < 19; ks++) {
    bf16x8 ah = *(const bf16x8*)(Ahp + ks * 32);
    bf16x8 al = *(const bf16x8*)(Alp + ks * 32);
    bf16x8 bh = *(const bf16x8*)(Bs + (ks * 2 + 0) * 512 + lane * 8);
    bf16x8 bl = *(const bf16x8*)(Bs + (ks * 2 + 1) * 512 + lane * 8);
    acc = __builtin_amdgcn_mfma_f32_16x16x32_bf16(ah, bh, acc, 0, 0, 0);
    acc = __builtin_amdgcn_mfma_f32_16x16x32_bf16(ah, bl, acc, 0, 0, 0);
    acc = __builtin_amdgcn_mfma_f32_16x16x32_bf16(al, bh, acc, 0, 0, 0);
  }

  int crow0 = m0 + kg * 4;
#pragma unroll
  for (int rr = 0; rr < 4; rr++) {
    unsigned short hh, ll;
    split_bf16(acc[rr], hh, ll);
    zhi[(size_t)(crow0 + rr) * KIR_ + nt * 16 + row] = hh;
    zlo[(size_t)(crow0 + rr) * KIR_ + nt * 16 + row] = ll;
  }
  if (nt == 12) {
    for (int cc = 208 + kg; cc < KIR_; cc += 4) {
      zhi[(size_t)(m0 + row) * KIR_ + cc] = 0;
      zlo[(size_t)(m0 + row) * KIR_ + cc] = 0;
    }
  }
}

// ---------------------------------------------------------------------------
// kIrfftEpi: irfft GEMM fused with the transpose epilogue.
// Block = (h-tile nt, 64-bc tile), 4 waves.  After MFMA, acc goes through an
// LDS [64][17] transpose; the epilogue applies (yhn+y)*sd+mu and stores out
// coalesced over c.  Eliminates the y buffer + kEpi.
// ---------------------------------------------------------------------------
__launch_bounds__(256)
__global__ void kIrfftEpi(const unsigned short* __restrict__ zhi,
                          const unsigned short* __restrict__ zlo,
                          const unsigned short* __restrict__ thi,
                          const unsigned short* __restrict__ tlo,
                          const float* __restrict__ seq, const float* __restrict__ mu,
                          const float* __restrict__ stdv, float* __restrict__ out) {
  __shared__ __align__(16) unsigned short Bs[14 * 512];
  __shared__ float ytile[64][17];
  int tid = threadIdx.x;
  int wv = tid >> 6;
  int lane = tid & 63;
  int nt = blockIdx.x;            // 12 h-tiles
  int mblk = blockIdx.y * 64;     // 64 bc per block
  int m0 = mblk + wv * 16;
  int row = lane & 15;
  int kg = lane >> 4;

  for (int s = wv; s < 14; s += 4) {
    int plane = s & 1;
    int ks = s >> 1;
    const unsigned short* src = (plane ? tlo : thi)
        + (size_t)(nt * 16 + row) * KIR_ + ks * 32 + kg * 8;
    *(bf16x8*)(Bs + s * 512 + lane * 8) = *(const bf16x8*)src;
  }
  __syncthreads();

  f32x4 acc = (f32x4){0.f, 0.f, 0.f, 0.f};
  int ar = (m0 + row < MPADF_) ? (m0 + row) : (MPADF_ - 1);   // clamp pad reads
  const unsigned short* Ahp = zhi + (size_t)ar * KIR_ + kg * 8;
  const unsigned short* Alp = zlo + (size_t)ar * KIR_ + kg * 8;

#pragma unroll
  for (int ks = 0; ks < 7; ks++) {
    bf16x8 ah = *(const bf16x8*)(Ahp + ks * 32);
    bf16x8 al = *(const bf16x8*)(Alp + ks * 32);
    bf16x8 bh = *(const bf16x8*)(Bs + (ks * 2 + 0) * 512 + lane * 8);
    bf16x8 bl = *(const bf16x8*)(Bs + (ks * 2 + 1) * 512 + lane * 8);
    acc = __builtin_amdgcn_mfma_f32_16x16x32_bf16(ah, bh, acc, 0, 0, 0);
    acc = __builtin_amdgcn_mfma_f32_16x16x32_bf16(ah, bl, acc, 0, 0, 0);
    acc = __builtin_amdgcn_mfma_f32_16x16x32_bf16(al, bh, acc, 0, 0, 0);
  }

  int ml0 = wv * 16 + kg * 4;
#pragma unroll
  for (int rr = 0; rr < 4; rr++) ytile[ml0 + rr][row] = acc[rr];
  __syncthreads();

  int ml = tid & 63;
  int bc = mblk + ml;
  if (bc < BC_) {
    int b = bc / C_;
    int c = bc - b * C_;
    float m = mu[bc], sd = stdv[bc];
    const float* sq = seq + (size_t)bc * SEQLEN_ + L_;
#pragma unroll
    for (int q = 0; q < 4; q++) {
      int hl = (tid >> 6) * 4 + q;
      int h = nt * 16 + hl;
      out[((size_t)b * H_ + h) * C_ + c] = fmaf(sq[h] + ytile[ml][hl], sd, m);
    }
  }
}

// ---------------------------------------------------------------------------
extern "C" void kernel_launch(void* const* d_in, const int* in_sizes, int n_in,
                              void* d_out, int out_size, void* d_ws, size_t ws_size,
                              hipStream_t stream) {
  const float* x           = (const float*)d_in[0];
  const float* y_hat       = (const float*)d_in[1];
  const int*   lead        = (const int*)d_in[2];
  const int*   shiftv      = (const int*)d_in[3];
  const float* r           = (const float*)d_in[4];
  const float* temperature = (const float*)d_in[5];
  const float* cls_w       = (const float*)d_in[6];
  const float* cls_bias    = (const float*)d_in[7];
  const float* basic_state = (const float*)d_in[8];
  const float* mh_w        = (const float*)d_in[9];
  const float* mh_b        = (const float*)d_in[10];
  const float* mwr         = (const float*)d_in[11];
  const float* mwi         = (const float*)d_in[12];
  const float* mbr         = (const float*)d_in[13];
  const float* mbi         = (const float*)d_in[14];
  float* out = (float*)d_out;
  float* ws  = (float*)d_ws;

  unsigned short* bphi = (unsigned short*)(ws + OFF_BPHI);
  unsigned short* bplo = (unsigned short*)(ws + OFF_BPLO);
  unsigned short* uhi  = (unsigned short*)(ws + OFF_UHI);
  unsigned short* ulo  = (unsigned short*)(ws + OFF_ULO);
  unsigned short* w2hi = (unsigned short*)(ws + OFF_W2HI);
  unsigned short* w2lo = (unsigned short*)(ws + OFF_W2LO);
  unsigned short* mwhi = (unsigned short*)(ws + OFF_MWHI);
  unsigned short* mwlo = (unsigned short*)(ws + OFF_MWLO);
  unsigned short* thi  = (unsigned short*)(ws + OFF_THI);
  unsigned short* tlo  = (unsigned short*)(ws + OFF_TLO);
  unsigned short* mxhi = (unsigned short*)(ws + OFF_MXHI);
  unsigned short* mxlo = (unsigned short*)(ws + OFF_MXLO);
  unsigned short* zhi  = (unsigned short*)(ws + OFF_ZHI);
  unsigned short* zlo  = (unsigned short*)(ws + OFF_ZLO);

  dim3 gP(B_, 6);
  kPre<<<gP, 256, 0, stream>>>(x, y_hat, cls_w, cls_bias, basic_state, r,
                               temperature, ws + OFF_MU, ws + OFF_STD,
                               uhi, ulo, ws + OFF_SEQ);

  const int TPK = NP_ * 192 + NPADF_ * KF_ + NMX_ * KMX_ + NIR_ * KIR_;
  kPackAll<<<(TPK + 255) / 256, 256, 0, stream>>>(mh_w, mh_b, mwr, mwi, mbr, mbi,
                                                  bphi, bplo, w2hi, w2lo,
                                                  mwhi, mwlo, thi, tlo);

  kGatherDFT<<<BC_ / 4, 320, 0, stream>>>(ws + OFF_SEQ, lead, shiftv, r,
                                          bphi, bplo, ws + OFF_F);

  dim3 gFM(NPADF_ / 64, (MPADF_ / 16 + 3) / 4);
  kFiltMM<<<gFM, 256, 0, stream>>>(uhi, ulo, w2hi, w2lo, ws + OFF_FILT);

  kCombine<<<BC_, 128, 0, stream>>>(ws + OFF_F, ws + OFF_FILT, mxhi, mxlo);

  dim3 gMX(13, 41);
  kMixMM<<<gMX, 256, 0, stream>>>(mxhi, mxlo, mwhi, mwlo, zhi, zlo);

  dim3 gIR(12, 41);
  kIrfftEpi<<<gIR, 256, 0, stream>>>(zhi, zlo, thi, tlo, ws + OFF_SEQ,
                                     ws + OFF_MU, ws + OFF_STD, out);
}

// Round 12
// 235.200 us; speedup vs baseline: 1.1844x; 1.1844x over previous
//
#include <hip/hip_runtime.h>
#include <math.h>

#define B_ 8
#define L_ 336
#define H_ 192
#define C_ 321
#define K_ 16
#define S_ 8
#define H2_ 97
#define OUT_ 3201
#define SEQLEN_ 528
#define BC_ (B_ * C_)
#define JD_ 136
#define MIXJ_ 291
#define NP_ 208
#define MROWS_ 43656
#define KF_ 160
#define MPADF_ 2576
#define NPADF_ 3264
#define KMX_ 608
#define NMX_ 208
#define KIR_ 224
#define NIR_ 192

typedef float v2f __attribute__((ext_vector_type(2)));
typedef float v4f __attribute__((ext_vector_type(4)));
typedef __attribute__((ext_vector_type(8))) short bf16x8;
typedef __attribute__((ext_vector_type(4))) float f32x4;

#define TWO_PI_F 6.283185307179586f

// ws layout (float units)
static constexpr size_t OFF_SEQ  = 0;
static constexpr size_t OFF_MU   = OFF_SEQ + (size_t)BC_ * SEQLEN_;
static constexpr size_t OFF_STD  = OFF_MU + BC_;
static constexpr size_t OFF_BPHI = (OFF_STD + BC_ + 3) & ~(size_t)3;
static constexpr size_t OFF_BPLO = OFF_BPHI + (size_t)NP_ * 192 / 2;
static constexpr size_t OFF_UHI  = OFF_BPLO + (size_t)NP_ * 192 / 2;
static constexpr size_t OFF_ULO  = OFF_UHI + (size_t)MPADF_ * KF_ / 2;
static constexpr size_t OFF_W2HI = OFF_ULO + (size_t)MPADF_ * KF_ / 2;
static constexpr size_t OFF_W2LO = OFF_W2HI + (size_t)NPADF_ * KF_ / 2;
static constexpr size_t OFF_MWHI = OFF_W2LO + (size_t)NPADF_ * KF_ / 2;
static constexpr size_t OFF_MWLO = OFF_MWHI + (size_t)NMX_ * KMX_ / 2;
static constexpr size_t OFF_THI  = OFF_MWLO + (size_t)NMX_ * KMX_ / 2;
static constexpr size_t OFF_TLO  = OFF_THI + (size_t)NIR_ * KIR_ / 2;
static constexpr size_t OFF_F    = OFF_TLO + (size_t)NIR_ * KIR_ / 2;
static constexpr size_t OFF_FILT = OFF_F + (size_t)MROWS_ * NP_;
static constexpr size_t OFF_MXHI = OFF_FILT + (size_t)BC_ * OUT_;
static constexpr size_t OFF_MXLO = OFF_MXHI + (size_t)MPADF_ * KMX_ / 2;
static constexpr size_t OFF_ZHI  = OFF_MXLO + (size_t)MPADF_ * KMX_ / 2;
static constexpr size_t OFF_ZLO  = OFF_ZHI + (size_t)MPADF_ * KIR_ / 2;

__device__ inline void split_bf16(float v, unsigned short& hh, unsigned short& ll) {
  unsigned u = __float_as_uint(v);
  unsigned hb = (u + 0x7FFFu + ((u >> 16) & 1u)) & 0xFFFF0000u;
  float fh = __uint_as_float(hb);
  float fl = v - fh;
  unsigned u2 = __float_as_uint(fl);
  unsigned lb = (u2 + 0x7FFFu + ((u2 >> 16) & 1u)) >> 16;
  hh = (unsigned short)(hb >> 16);
  ll = (unsigned short)lb;
}

// ---------------------------------------------------------------------------
// kStats: block = (b, 64-c tile), 256 thr.  stats + softmax + corr_feat + U.
// (round-10 validated version)
// ---------------------------------------------------------------------------
__launch_bounds__(256)
__global__ void kStats(const float* __restrict__ x, const float* __restrict__ cls_w,
                       const float* __restrict__ cls_bias,
                       const float* __restrict__ basic_state, const float* __restrict__ r,
                       const float* __restrict__ temperature,
                       float* __restrict__ mu, float* __restrict__ stdv,
                       unsigned short* __restrict__ uhi, unsigned short* __restrict__ ulo) {
  __shared__ float part[4][10][64];
  __shared__ float sp[64][S_];
  __shared__ float scf[64][K_];

  int b = blockIdx.x;
  int cb = blockIdx.y * 64;
  int lane = threadIdx.x & 63;
  int wv = threadIdx.x >> 6;
  int c = cb + lane;
  bool cok = c < C_;

  float sum = 0.f, sumsq = 0.f, a[S_];
#pragma unroll
  for (int s = 0; s < S_; s++) a[s] = 0.f;
  if (cok) {
    for (int l = wv * 84; l < wv * 84 + 84; l++) {
      float v = x[((size_t)b * L_ + l) * C_ + c];
      sum += v;
      sumsq = fmaf(v, v, sumsq);
#pragma unroll
      for (int s = 0; s < S_; s++) a[s] = fmaf(v, cls_w[s * L_ + l], a[s]);
    }
  }
  part[wv][0][lane] = sum;
  part[wv][1][lane] = sumsq;
#pragma unroll
  for (int s = 0; s < S_; s++) part[wv][2 + s][lane] = a[s];
  __syncthreads();

  if (threadIdx.x < 64 && cok) {
    float s0 = 0.f, s1 = 0.f, ac[S_];
#pragma unroll
    for (int s = 0; s < S_; s++) ac[s] = 0.f;
#pragma unroll
    for (int w = 0; w < 4; w++) {
      s0 += part[w][0][lane];
      s1 += part[w][1][lane];
#pragma unroll
      for (int s = 0; s < S_; s++) ac[s] += part[w][2 + s][lane];
    }
    float m = s0 * (1.f / L_);
    float var = fmaxf(s1 * (1.f / L_) - m * m, 0.f);
    float sd = sqrtf(var + 1e-8f);
    int bc = b * C_ + c;
    mu[bc] = m;
    stdv[bc] = sd;

    float lg[S_], mx = -1e30f;
#pragma unroll
    for (int s = 0; s < S_; s++) {
      lg[s] = ac[s] + cls_bias[s] + basic_state[c * S_ + s];
      mx = fmaxf(mx, lg[s]);
    }
    float den = 0.f;
#pragma unroll
    for (int s = 0; s < S_; s++) { float e = expf(lg[s] - mx); lg[s] = e; den += e; }
    float iden = 1.f / den;
#pragma unroll
    for (int s = 0; s < S_; s++) sp[lane][s] = lg[s] * iden;

    float it = 1.f / temperature[0];
    float aa[K_], am = it;
#pragma unroll
    for (int k = 0; k < K_; k++) {
      aa[k] = fabsf(r[(size_t)bc * K_ + k]) * it;
      am = fmaxf(am, aa[k]);
    }
    float den2 = expf(it - am);
#pragma unroll
    for (int k = 0; k < K_; k++) { float e = expf(aa[k] - am); aa[k] = e; den2 += e; }
    float iden2 = 1.f / den2;
#pragma unroll
    for (int k = 0; k < K_; k++) scf[lane][k] = aa[k] * iden2;
  }
  __syncthreads();

  for (int idx = threadIdx.x; idx < 64 * KF_; idx += 256) {
    int ci = idx / KF_;
    int j = idx - ci * KF_;
    if (cb + ci < C_) {
      float v = 0.f;
      if (j < JD_) {
        int s = j / 17;
        int t = j - s * 17;
        v = sp[ci][s];
        if (t < K_) v *= scf[ci][t];
      }
      unsigned short hh, ll;
      split_bf16(v, hh, ll);
      size_t row = (size_t)(b * C_ + cb + ci) * KF_ + j;
      uhi[row] = hh;
      ulo[row] = ll;
    }
  }
}

// ---------------------------------------------------------------------------
// kSeqT: normalized seq via 32x32 LDS transpose tiles.  grid (B, 11, 17).
// (round-10 validated version)
// ---------------------------------------------------------------------------
__launch_bounds__(256)
__global__ void kSeqT(const float* __restrict__ x, const float* __restrict__ y_hat,
                      const float* __restrict__ mu, const float* __restrict__ stdv,
                      float* __restrict__ seq) {
  __shared__ float tile[32][33];
  int b = blockIdx.x;
  int cb = blockIdx.y * 32;
  int tb = blockIdx.z * 32;
  int ci = threadIdx.x & 31;
  int q8 = threadIdx.x >> 5;
  int c = cb + ci;
  float m = 0.f, is = 0.f;
  if (c < C_) {
    m = mu[b * C_ + c];
    is = 1.f / stdv[b * C_ + c];
  }
#pragma unroll
  for (int q = 0; q < 4; q++) {
    int tt = q8 + q * 8;
    int t = tb + tt;
    float v = 0.f;
    if (c < C_ && t < SEQLEN_)
      v = (t < L_) ? x[((size_t)b * L_ + t) * C_ + c]
                   : y_hat[((size_t)b * H_ + (t - L_)) * C_ + c];
    tile[ci][tt] = (v - m) * is;
  }
  __syncthreads();
#pragma unroll
  for (int q = 0; q < 4; q++) {
    int cc = cb + q8 + q * 8;
    int t = tb + ci;
    if (cc < C_ && t < SEQLEN_)
      seq[((size_t)b * C_ + cc) * SEQLEN_ + t] = tile[q8 + q * 8][ci];
  }
}

// ---------------------------------------------------------------------------
// kPackAll: all 4 constant-matrix packs in one launch.  (round-11, kept)
// ---------------------------------------------------------------------------
__global__ void kPackAll(const float* __restrict__ mh_w, const float* __restrict__ mh_b,
                         const float* __restrict__ mwr, const float* __restrict__ mwi,
                         const float* __restrict__ mbr, const float* __restrict__ mbi,
                         unsigned short* __restrict__ bhi, unsigned short* __restrict__ blo,
                         unsigned short* __restrict__ w2hi, unsigned short* __restrict__ w2lo,
                         unsigned short* __restrict__ mwhi, unsigned short* __restrict__ mwlo,
                         unsigned short* __restrict__ thi, unsigned short* __restrict__ tlo) {
  const int T1 = NP_ * 192;
  const int T2 = T1 + NPADF_ * KF_;
  const int T3 = T2 + NMX_ * KMX_;
  const int T4 = T3 + NIR_ * KIR_;
  int i = blockIdx.x * 256 + threadIdx.x;
  if (i >= T4) return;
  float v = 0.f;
  unsigned short* dhi;
  unsigned short* dlo;
  int didx;
  if (i < T1) {
    int n = i / 192, h = i - n * 192;
    if (n < H2_) {
      int ph = (n * h) % 192;
      v = cosf((TWO_PI_F / 192.f) * (float)ph);
    } else if (n >= 104 && n < 104 + H2_) {
      int ph = ((n - 104) * h) % 192;
      v = -sinf((TWO_PI_F / 192.f) * (float)ph);
    }
    dhi = bhi; dlo = blo; didx = i;
  } else if (i < T2) {
    int idx = i - T1;
    int n = idx / KF_, k = idx - n * KF_;
    if (n < OUT_ && k < JD_) {
      int s = k / 17, t = k - s * 17;
      v = (t < K_) ? mh_w[(size_t)s * (K_ * OUT_) + (size_t)t * OUT_ + n]
                   : mh_b[(size_t)s * OUT_ + n];
    }
    dhi = w2hi; dlo = w2lo; didx = idx;
  } else if (i < T3) {
    int idx = i - T2;
    int n = idx / KMX_, k = idx - n * KMX_;
    if (n < H2_) {
      int g = n;
      if (k < MIXJ_) v = mwr[(size_t)g * MIXJ_ + k];
      else if (k < 2 * MIXJ_) v = -mwi[(size_t)g * MIXJ_ + (k - MIXJ_)];
      else if (k == 2 * MIXJ_) v = mbr[g];
    } else if (n >= 104 && n < 104 + H2_) {
      int g = n - 104;
      if (k < MIXJ_) v = mwi[(size_t)g * MIXJ_ + k];
      else if (k < 2 * MIXJ_) v = mwr[(size_t)g * MIXJ_ + (k - MIXJ_)];
      else if (k == 2 * MIXJ_) v = mbi[g];
    }
    dhi = mwhi; dlo = mwlo; didx = idx;
  } else {
    int idx = i - T3;
    int h = idx / KIR_, k = idx - h * KIR_;
    if (k < H2_) {
      int f = k;
      float w = (f == 0 || f == 96) ? (1.f / 192.f) : (2.f / 192.f);
      int ph = (f * h) % 192;
      v = w * cosf((TWO_PI_F / 192.f) * (float)ph);
    } else if (k >= 104 && k < 104 + H2_) {
      int f = k - 104;
      if (f != 0 && f != 96) {
        int ph = (f * h) % 192;
        v = -(2.f / 192.f) * sinf((TWO_PI_F / 192.f) * (float)ph);
      }
    }
    dhi = thi; dlo = tlo; didx = idx;
  }
  unsigned short hh, ll;
  split_bf16(v, hh, ll);
  dhi[didx] = hh;
  dlo[didx] = ll;
}

// ---------------------------------------------------------------------------
// kGatherDFT: fused leader-gather + DFT GEMM.  (round-11, kept)
// ---------------------------------------------------------------------------
__launch_bounds__(320)
__global__ void kGatherDFT(const float* __restrict__ seq, const int* __restrict__ lead,
                           const int* __restrict__ shiftv, const float* __restrict__ r,
                           const unsigned short* __restrict__ bhi,
                           const unsigned short* __restrict__ blo,
                           float* __restrict__ F) {
  __shared__ __align__(16) unsigned short Ah[80 * 200];
  __shared__ __align__(16) unsigned short Al[80 * 200];
  __shared__ __align__(16) unsigned short Bs[52 * 512];
  __shared__ int soff[68];
  __shared__ float ssgn[68];

  int tid = threadIdx.x;
  int wv = tid >> 6;
  int lane = tid & 63;
  int bc0 = blockIdx.x * 4;

  if (tid < 68) {
    int lr = tid;
    int bcl = lr / 17;
    int k = lr - bcl * 17;
    int bc = bc0 + bcl;
    int b = bc / C_;
    int off;
    float sg;
    if (k < K_) {
      int ld = lead[(size_t)bc * K_ + k];
      int sh = shiftv[(size_t)bc * K_ + k];
      float rv = r[(size_t)bc * K_ + k];
      sg = (rv > 0.f) ? 1.f : ((rv < 0.f) ? -1.f : 0.f);
      off = (b * C_ + ld) * SEQLEN_ + (L_ - sh);
    } else {
      sg = 1.f;
      off = bc * SEQLEN_ + L_;
    }
    soff[lr] = off;
    ssgn[lr] = sg;
  }
  __syncthreads();

  for (int idx = tid; idx < 68 * 192; idx += 320) {
    int lr = idx / 192;
    int h = idx - lr * 192;
    float v = seq[soff[lr] + h] * ssgn[lr];
    unsigned short hh, ll;
    split_bf16(v, hh, ll);
    Ah[lr * 200 + h] = hh;
    Al[lr * 200 + h] = ll;
  }
  for (int i = 68 * 200 + tid; i < 80 * 200; i += 320) { Ah[i] = 0; Al[i] = 0; }

  int row = lane & 15;
  int kg = lane >> 4;
  f32x4 acc[13];
#pragma unroll
  for (int nt = 0; nt < 13; nt++) acc[nt] = (f32x4){0.f, 0.f, 0.f, 0.f};

  const unsigned short* Abh = Ah + (wv * 16 + row) * 200 + kg * 8;
  const unsigned short* Abl = Al + (wv * 16 + row) * 200 + kg * 8;

#pragma unroll 1
  for (int part = 0; part < 3; part++) {
    __syncthreads();
    for (int s = wv; s < 52; s += 5) {
      int plane = s & 1;
      int ntks = s >> 1;
      int nt = ntks >> 1;
      int ks2 = ntks & 1;
      const unsigned short* src = (plane ? blo : bhi)
          + (size_t)(nt * 16 + row) * 192 + part * 64 + ks2 * 32 + kg * 8;
      *(bf16x8*)(Bs + s * 512 + lane * 8) = *(const bf16x8*)src;
    }
    __syncthreads();
#pragma unroll
    for (int ks2 = 0; ks2 < 2; ks2++) {
      int ksg = part * 2 + ks2;
      bf16x8 ah = *(const bf16x8*)(Abh + ksg * 32);
      bf16x8 al = *(const bf16x8*)(Abl + ksg * 32);
#pragma unroll
      for (int nt = 0; nt < 13; nt++) {
        bf16x8 bh = *(const bf16x8*)(Bs + ((nt * 2 + ks2) * 2 + 0) * 512 + lane * 8);
        bf16x8 bl = *(const bf16x8*)(Bs + ((nt * 2 + ks2) * 2 + 1) * 512 + lane * 8);
        acc[nt] = __builtin_amdgcn_mfma_f32_16x16x32_bf16(ah, bh, acc[nt], 0, 0, 0);
        acc[nt] = __builtin_amdgcn_mfma_f32_16x16x32_bf16(ah, bl, acc[nt], 0, 0, 0);
        acc[nt] = __builtin_amdgcn_mfma_f32_16x16x32_bf16(al, bh, acc[nt], 0, 0, 0);
      }
    }
  }

  int ml0 = wv * 16 + kg * 4;
#pragma unroll
  for (int nt = 0; nt < 13; nt++) {
#pragma unroll
    for (int rr = 0; rr < 4; rr++) {
      int ml = ml0 + rr;
      if (ml < 68)
        F[((size_t)bc0 * 17 + ml) * NP_ + nt * 16 + row] = acc[nt][rr];
    }
  }
}

// ---------------------------------------------------------------------------
// kFiltMM: filt GEMM, W2 tile staged in LDS (40 KB).  (validated)
// ---------------------------------------------------------------------------
__launch_bounds__(256)
__global__ void kFiltMM(const unsigned short* __restrict__ uhi,
                        const unsigned short* __restrict__ ulo,
                        const unsigned short* __restrict__ w2hi,
                        const unsigned short* __restrict__ w2lo,
                        float* __restrict__ filt) {
  __shared__ __align__(16) unsigned short Ws[40 * 512];
  int tid = threadIdx.x;
  int wv = tid >> 6;
  int lane = tid & 63;
  int m0 = (blockIdx.y * 4 + wv) * 16;
  int n0 = blockIdx.x * 64;
  int col = lane & 15;
  int kg = lane >> 4;

  for (int s = wv; s < 40; s += 4) {
    int plane = s & 1;
    int ntk = s >> 1;
    int nt = ntk / 5;
    int ksi = ntk - nt * 5;
    const unsigned short* src = (plane ? w2lo : w2hi)
        + (size_t)(n0 + nt * 16 + col) * KF_ + ksi * 32 + kg * 8;
    *(bf16x8*)(Ws + s * 512 + lane * 8) = *(const bf16x8*)src;
  }
  __syncthreads();

  f32x4 acc[4];
#pragma unroll
  for (int nt = 0; nt < 4; nt++) acc[nt] = (f32x4){0.f, 0.f, 0.f, 0.f};

  int mrow = (m0 + col < MPADF_) ? (m0 + col) : (MPADF_ - 1);
  const unsigned short* Ahp = uhi + (size_t)mrow * KF_ + kg * 8;
  const unsigned short* Alp = ulo + (size_t)mrow * KF_ + kg * 8;

#pragma unroll
  for (int ks = 0; ks < 5; ks++) {
    bf16x8 ah = *(const bf16x8*)(Ahp + ks * 32);
    bf16x8 al = *(const bf16x8*)(Alp + ks * 32);
#pragma unroll
    for (int nt = 0; nt < 4; nt++) {
      bf16x8 bh = *(const bf16x8*)(Ws + ((nt * 5 + ks) * 2 + 0) * 512 + lane * 8);
      bf16x8 bl = *(const bf16x8*)(Ws + ((nt * 5 + ks) * 2 + 1) * 512 + lane * 8);
      acc[nt] = __builtin_amdgcn_mfma_f32_16x16x32_bf16(ah, bh, acc[nt], 0, 0, 0);
      acc[nt] = __builtin_amdgcn_mfma_f32_16x16x32_bf16(ah, bl, acc[nt], 0, 0, 0);
      acc[nt] = __builtin_amdgcn_mfma_f32_16x16x32_bf16(al, bh, acc[nt], 0, 0, 0);
    }
  }

  int crow0 = m0 + kg * 4;
#pragma unroll
  for (int nt = 0; nt < 4; nt++) {
    int o = n0 + nt * 16 + col;
    if (o < OUT_) {
#pragma unroll
      for (int rr = 0; rr < 4; rr++) {
        int m = crow0 + rr;
        if (m < BC_) filt[(size_t)m * OUT_ + o] = acc[nt][rr];
      }
    }
  }
}

// ---------------------------------------------------------------------------
// kCombine: per bc (128 thr): filt combine -> mix_in bf16 planes. (validated)
// ---------------------------------------------------------------------------
__launch_bounds__(128)
__global__ void kCombine(const float* __restrict__ F, const float* __restrict__ filt,
                         unsigned short* __restrict__ mxhi, unsigned short* __restrict__ mxlo) {
  int bc = blockIdx.x;
  int ff = threadIdx.x;
  size_t mrowK = (size_t)bc * KMX_;

  if (ff < H2_) {
    float Fre[17], Fim[17];
#pragma unroll
    for (int k = 0; k < 17; k++) {
      size_t mr = (size_t)(bc * 17 + k) * NP_;
      Fre[k] = F[mr + ff];
      Fim[k] = F[mr + 104 + ff];
    }
    const float* fb = filt + (size_t)bc * OUT_;
    float yfR = Fre[16], yfI = Fim[16];
    float S1r = 0.f, S1i = 0.f, S2r = 0.f, S2i = 0.f, sg2 = 0.f;
#pragma unroll
    for (int k = 0; k < K_; k++) {
      float g1 = fb[k * H2_ + ff];
      float g2 = fb[(K_ + k) * H2_ + ff];
      float g12 = g1 * g2;
      S1r = fmaf(Fre[k], g1, S1r);
      S1i = fmaf(Fim[k], g1, S1i);
      S2r = fmaf(Fre[k], g12, S2r);
      S2i = fmaf(Fim[k], g12, S2i);
      sg2 += g2;
    }
    S2r = fmaf(-yfR, sg2, S2r);
    S2i = fmaf(-yfI, sg2, S2i);
    float g3 = fb[32 * H2_ + ff];
    float vals[6] = {S1r, S2r, yfR * g3, S1i, S2i, yfI * g3};
#pragma unroll
    for (int q = 0; q < 6; q++) {
      unsigned short hh, ll;
      split_bf16(vals[q], hh, ll);
      mxhi[mrowK + q * H2_ + ff] = hh;
      mxlo[mrowK + q * H2_ + ff] = ll;
    }
  } else if (ff == H2_) {
    mxhi[mrowK + 2 * MIXJ_] = 0x3F80;  // bf16(1.0) bias
    mxlo[mrowK + 2 * MIXJ_] = 0;
  } else if (ff >= 98 && ff < 98 + (KMX_ - 583)) {
    int k = 583 + (ff - 98);
    mxhi[mrowK + k] = 0;
    mxlo[mrowK + k] = 0;
  }
}

// ---------------------------------------------------------------------------
// kMixMM: z GEMM (validated).
// ---------------------------------------------------------------------------
__launch_bounds__(256)
__global__ void kMixMM(const unsigned short* __restrict__ mxhi,
                       const unsigned short* __restrict__ mxlo,
                       const unsigned short* __restrict__ mwhi,
                       const unsigned short* __restrict__ mwlo,
                       unsigned short* __restrict__ zhi, unsigned short* __restrict__ zlo) {
  __shared__ __align__(16) unsigned short Bs[38 * 512];
  int tid = threadIdx.x;
  int wv = tid >> 6;
  int lane = tid & 63;
  int nt = blockIdx.x;
  int m0 = (blockIdx.y * 4 + wv) * 16;
  int row = lane & 15;
  int kg = lane >> 4;

  for (int s = wv; s < 38; s += 4) {
    int plane = s & 1;
    int ks = s >> 1;
    const unsigned short* src = (plane ? mwlo : mwhi)
        + (size_t)(nt * 16 + row) * KMX_ + ks * 32 + kg * 8;
    *(bf16x8*)(Bs + s * 512 + lane * 8) = *(const bf16x8*)src;
  }
  __syncthreads();

  if (m0 >= MPADF_) return;

  f32x4 acc = (f32x4){0.f, 0.f, 0.f, 0.f};
  const unsigned short* Ahp = mxhi + (size_t)(m0 + row) * KMX_ + kg * 8;
  const unsigned short* Alp = mxlo + (size_t)(m0 + row) * KMX_ + kg * 8;

#pragma unroll
  for (int ks = 0; ks < 19; ks++) {
    bf16x8 ah = *(const bf16x8*)(Ahp + ks * 32);
    bf16x8 al = *(const bf16x8*)(Alp + ks * 32);
    bf16x8 bh = *(const bf16x8*)(Bs + (ks * 2 + 0) * 512 + lane * 8);
    bf16x8 bl = *(const bf16x8*)(Bs + (ks * 2 + 1) * 512 + lane * 8);
    acc = __builtin_amdgcn_mfma_f32_16x16x32_bf16(ah, bh, acc, 0, 0, 0);
    acc = __builtin_amdgcn_mfma_f32_16x16x32_bf16(ah, bl, acc, 0, 0, 0);
    acc = __builtin_amdgcn_mfma_f32_16x16x32_bf16(al, bh, acc, 0, 0, 0);
  }

  int crow0 = m0 + kg * 4;
#pragma unroll
  for (int rr = 0; rr < 4; rr++) {
    unsigned short hh, ll;
    split_bf16(acc[rr], hh, ll);
    zhi[(size_t)(crow0 + rr) * KIR_ + nt * 16 + row] = hh;
    zlo[(size_t)(crow0 + rr) * KIR_ + nt * 16 + row] = ll;
  }
  if (nt == 12) {
    for (int cc = 208 + kg; cc < KIR_; cc += 4) {
      zhi[(size_t)(m0 + row) * KIR_ + cc] = 0;
      zlo[(size_t)(m0 + row) * KIR_ + cc] = 0;
    }
  }
}

// ---------------------------------------------------------------------------
// kIrfftEpi: irfft GEMM fused with transpose epilogue.  (round-11, kept)
// ---------------------------------------------------------------------------
__launch_bounds__(256)
__global__ void kIrfftEpi(const unsigned short* __restrict__ zhi,
                          const unsigned short* __restrict__ zlo,
                          const unsigned short* __restrict__ thi,
                          const unsigned short* __restrict__ tlo,
                          const float* __restrict__ seq, const float* __restrict__ mu,
                          const float* __restrict__ stdv, float* __restrict__ out) {
  __shared__ __align__(16) unsigned short Bs[14 * 512];
  __shared__ float ytile[64][17];
  int tid = threadIdx.x;
  int wv = tid >> 6;
  int lane = tid & 63;
  int nt = blockIdx.x;
  int mblk = blockIdx.y * 64;
  int m0 = mblk + wv * 16;
  int row = lane & 15;
  int kg = lane >> 4;

  for (int s = wv; s < 14; s += 4) {
    int plane = s & 1;
    int ks = s >> 1;
    const unsigned short* src = (plane ? tlo : thi)
        + (size_t)(nt * 16 + row) * KIR_ + ks * 32 + kg * 8;
    *(bf16x8*)(Bs + s * 512 + lane * 8) = *(const bf16x8*)src;
  }
  __syncthreads();

  f32x4 acc = (f32x4){0.f, 0.f, 0.f, 0.f};
  int ar = (m0 + row < MPADF_) ? (m0 + row) : (MPADF_ - 1);
  const unsigned short* Ahp = zhi + (size_t)ar * KIR_ + kg * 8;
  const unsigned short* Alp = zlo + (size_t)ar * KIR_ + kg * 8;

#pragma unroll
  for (int ks = 0; ks < 7; ks++) {
    bf16x8 ah = *(const bf16x8*)(Ahp + ks * 32);
    bf16x8 al = *(const bf16x8*)(Alp + ks * 32);
    bf16x8 bh = *(const bf16x8*)(Bs + (ks * 2 + 0) * 512 + lane * 8);
    bf16x8 bl = *(const bf16x8*)(Bs + (ks * 2 + 1) * 512 + lane * 8);
    acc = __builtin_amdgcn_mfma_f32_16x16x32_bf16(ah, bh, acc, 0, 0, 0);
    acc = __builtin_amdgcn_mfma_f32_16x16x32_bf16(ah, bl, acc, 0, 0, 0);
    acc = __builtin_amdgcn_mfma_f32_16x16x32_bf16(al, bh, acc, 0, 0, 0);
  }

  int ml0 = wv * 16 + kg * 4;
#pragma unroll
  for (int rr = 0; rr < 4; rr++) ytile[ml0 + rr][row] = acc[rr];
  __syncthreads();

  int ml = tid & 63;
  int bc = mblk + ml;
  if (bc < BC_) {
    int b = bc / C_;
    int c = bc - b * C_;
    float m = mu[bc], sd = stdv[bc];
    const float* sq = seq + (size_t)bc * SEQLEN_ + L_;
#pragma unroll
    for (int q = 0; q < 4; q++) {
      int hl = (tid >> 6) * 4 + q;
      int h = nt * 16 + hl;
      out[((size_t)b * H_ + h) * C_ + c] = fmaf(sq[h] + ytile[ml][hl], sd, m);
    }
  }
}

// ---------------------------------------------------------------------------
extern "C" void kernel_launch(void* const* d_in, const int* in_sizes, int n_in,
                              void* d_out, int out_size, void* d_ws, size_t ws_size,
                              hipStream_t stream) {
  const float* x           = (const float*)d_in[0];
  const float* y_hat       = (const float*)d_in[1];
  const int*   lead        = (const int*)d_in[2];
  const int*   shiftv      = (const int*)d_in[3];
  const float* r           = (const float*)d_in[4];
  const float* temperature = (const float*)d_in[5];
  const float* cls_w       = (const float*)d_in[6];
  const float* cls_bias    = (const float*)d_in[7];
  const float* basic_state = (const float*)d_in[8];
  const float* mh_w        = (const float*)d_in[9];
  const float* mh_b        = (const float*)d_in[10];
  const float* mwr         = (const float*)d_in[11];
  const float* mwi         = (const float*)d_in[12];
  const float* mbr         = (const float*)d_in[13];
  const float* mbi         = (const float*)d_in[14];
  float* out = (float*)d_out;
  float* ws  = (float*)d_ws;

  unsigned short* bphi = (unsigned short*)(ws + OFF_BPHI);
  unsigned short* bplo = (unsigned short*)(ws + OFF_BPLO);
  unsigned short* uhi  = (unsigned short*)(ws + OFF_UHI);
  unsigned short* ulo  = (unsigned short*)(ws + OFF_ULO);
  unsigned short* w2hi = (unsigned short*)(ws + OFF_W2HI);
  unsigned short* w2lo = (unsigned short*)(ws + OFF_W2LO);
  unsigned short* mwhi = (unsigned short*)(ws + OFF_MWHI);
  unsigned short* mwlo = (unsigned short*)(ws + OFF_MWLO);
  unsigned short* thi  = (unsigned short*)(ws + OFF_THI);
  unsigned short* tlo  = (unsigned short*)(ws + OFF_TLO);
  unsigned short* mxhi = (unsigned short*)(ws + OFF_MXHI);
  unsigned short* mxlo = (unsigned short*)(ws + OFF_MXLO);
  unsigned short* zhi  = (unsigned short*)(ws + OFF_ZHI);
  unsigned short* zlo  = (unsigned short*)(ws + OFF_ZLO);

  dim3 gS(B_, 6);
  kStats<<<gS, 256, 0, stream>>>(x, cls_w, cls_bias, basic_state, r, temperature,
                                 ws + OFF_MU, ws + OFF_STD, uhi, ulo);

  dim3 gT(B_, 11, 17);
  kSeqT<<<gT, 256, 0, stream>>>(x, y_hat, ws + OFF_MU, ws + OFF_STD, ws + OFF_SEQ);

  const int TPK = NP_ * 192 + NPADF_ * KF_ + NMX_ * KMX_ + NIR_ * KIR_;
  kPackAll<<<(TPK + 255) / 256, 256, 0, stream>>>(mh_w, mh_b, mwr, mwi, mbr, mbi,
                                                  bphi, bplo, w2hi, w2lo,
                                                  mwhi, mwlo, thi, tlo);

  kGatherDFT<<<BC_ / 4, 320, 0, stream>>>(ws + OFF_SEQ, lead, shiftv, r,
                                          bphi, bplo, ws + OFF_F);

  dim3 gFM(NPADF_ / 64, (MPADF_ / 16 + 3) / 4);
  kFiltMM<<<gFM, 256, 0, stream>>>(uhi, ulo, w2hi, w2lo, ws + OFF_FILT);

  kCombine<<<BC_, 128, 0, stream>>>(ws + OFF_F, ws + OFF_FILT, mxhi, mxlo);

  dim3 gMX(13, 41);
  kMixMM<<<gMX, 256, 0, stream>>>(mxhi, mxlo, mwhi, mwlo, zhi, zlo);

  dim3 gIR(12, 41);
  kIrfftEpi<<<gIR, 256, 0, stream>>>(zhi, zlo, thi, tlo, ws + OFF_SEQ,
                                     ws + OFF_MU, ws + OFF_STD, out);
}